// Round 9
// baseline (236.698 us; speedup 1.0000x reference)
//
#include <hip/hip_runtime.h>

#define IN_DIM 23
#define HID 128
#define OUTD 64
#define NGR 64
#define NXCD 8
#define FB_DIM 32      // feat padded to 32 bf16 = 64B aligned rows
#define PH_STRIDE 136  // 16 rows x 136 bf16: 272B row stride (16B-aligned, bank-spread)
#define A2_BLOCKS 2048
#define NB 256         // dst-range buckets for CSR build
#define CAP 8192       // records per bucket region (mean 6250, sd 79 -> +24 sigma)
#define CHUNK 4096     // edges staged per k_bin block (16/thread in regs)

typedef __attribute__((ext_vector_type(8))) short bf16x8;
typedef __attribute__((ext_vector_type(4))) float f32x4;
typedef __attribute__((ext_vector_type(2))) float f32x2;

static __device__ __forceinline__ unsigned xcd_id() {
    unsigned x;
    asm volatile("s_getreg_b32 %0, hwreg(20, 0, 32)" : "=s"(x));  // HW_REG_XCC_ID
    return x & (NXCD - 1);
}

static __device__ __forceinline__ unsigned short f2bf(float x) {
    unsigned u = __float_as_uint(x);
    unsigned r = (u + 0x7FFFu + ((u >> 16) & 1u)) >> 16;   // RNE
    return (unsigned short)r;
}
static __device__ __forceinline__ float bf2f(unsigned short u) {
    return __uint_as_float((unsigned)u << 16);             // exact
}

// ---- fp8 e4m3 (OCP) scalar encode: RNE, satfinite (fallback path) -----------
static __device__ __forceinline__ unsigned enc_fp8(float x) {
    float a = fabsf(x);
    unsigned s = (__float_as_uint(x) >> 31) << 7;
    if (!(a > 0.f)) return s;                    // zero
    a = fminf(a, 448.f);
    int eb; float fr = frexpf(a, &eb);           // a = fr*2^eb, fr in [0.5,1)
    int E = eb - 1;
    int code;
    if (E < -6) code = (int)rintf(ldexpf(a, 9)); // denormal path
    else        code = ((E + 7) << 3) + (int)rintf(ldexpf(fr, 4)) - 8;
    code = min(code, 0x7E);
    return s | (unsigned)code;
}

// ---- fp8 e4m3 pack 4: HW packed convert if available ------------------------
#if __has_builtin(__builtin_amdgcn_cvt_pk_fp8_f32)
static __device__ __forceinline__ unsigned enc4_fp8(float a, float b,
                                                    float c, float d) {
    int r = __builtin_amdgcn_cvt_pk_fp8_f32(a, b, 0, false);
    r = __builtin_amdgcn_cvt_pk_fp8_f32(c, d, r, true);
    return (unsigned)r;
}
#else
static __device__ __forceinline__ unsigned enc4_fp8(float a, float b,
                                                    float c, float d) {
    return enc_fp8(a) | (enc_fp8(b) << 8) | (enc_fp8(c) << 16)
         | (enc_fp8(d) << 24);
}
#endif

// ---- fp8 e4m3 decode 4 -> two packed f32x2 ----------------------------------
#if __has_builtin(__builtin_amdgcn_cvt_pk_f32_fp8)
static __device__ __forceinline__ void dec_pk(unsigned u, f32x2& lo, f32x2& hi) {
    lo = __builtin_amdgcn_cvt_pk_f32_fp8((int)u, false);
    hi = __builtin_amdgcn_cvt_pk_f32_fp8((int)u, true);
}
#else
static __device__ __forceinline__ float dec1_fp8(unsigned b) {
    unsigned s = (b & 0x80u) << 24;
    unsigned em = b & 0x7Fu;
    float f = __uint_as_float(s | ((em << 20) + 0x3C000000u));
    if ((b & 0x78u) == 0)
        f = 2.f * f - __uint_as_float(s | 0x3C800000u);
    return f;
}
static __device__ __forceinline__ void dec_pk(unsigned u, f32x2& lo, f32x2& hi) {
    lo[0] = dec1_fp8(u & 0xFF);        lo[1] = dec1_fp8((u >> 8) & 0xFF);
    hi[0] = dec1_fp8((u >> 16) & 0xFF); hi[1] = dec1_fp8(u >> 24);
}
#endif

// ---------------- A: fused prep: feat0 -> bf16 rows; W1/W2 transpose+pad -----
__global__ __launch_bounds__(256) void k_prep(
    const float* __restrict__ feat0, unsigned short* __restrict__ featb,
    const float* __restrict__ W1, const float* __restrict__ W2,
    unsigned short* __restrict__ W1t, unsigned short* __restrict__ W2t,
    int n_nodes)
{
    int i = blockIdx.x * 256 + threadIdx.x;
    int nf = n_nodes * FB_DIM;
    if (i < nf) {
        int v = i >> 5, d = i & (FB_DIM - 1);
        float x = (d < IN_DIM) ? feat0[(size_t)v * IN_DIM + d] : 0.f;
        featb[i] = f2bf(x);
    } else {
        int j = i - nf;
        if (j < HID * 32) {
            int h = j >> 5, d = j & 31;
            W1t[j] = f2bf((d < IN_DIM) ? W1[d * HID + h] : 0.f);
        } else if (j < HID * 32 + OUTD * HID) {
            int q = j - HID * 32;
            int o = q >> 7, k = q & 127;
            W2t[q] = f2bf(W2[k * OUTD + o]);
        }
    }
}

// ---------------- P1: bucket edges by dst range (regs -> LDS -> append) ------
// Append is PARALLEL: one global atomic per bucket reserves space; then all
// 256 threads grid-stride the staged records, binary-search their bucket in
// the scan array, and write contiguously -> ~64B-coalesced segments instead
// of R8's per-thread serial 4B stores.
__global__ __launch_bounds__(256) void k_bin(
    const int* __restrict__ src, const int* __restrict__ dst,
    unsigned* __restrict__ brec, int* __restrict__ bcur,
    int n_edges, int n_nodes)
{
    __shared__ int cnt[NB], offs[NB], cur[NB], gbs[NB];
    __shared__ unsigned stage[CHUNK];
    int t = threadIdx.x;
    int e0 = blockIdx.x * CHUNK;
    int e1 = min(e0 + CHUNK, n_edges);
    int total = e1 - e0;
    int myb[16];
    unsigned myrec[16];
    cnt[t] = 0;
    __syncthreads();
#pragma unroll
    for (int k = 0; k < 16; ++k) {
        int e = e0 + k * 256 + t;
        myb[k] = -1;
        if (e < e1) {
            int u = src[e], v = dst[e];
            int b = (v * NB) / n_nodes;                    // exact int div
            int vlo = (b * n_nodes + NB - 1) / NB;
            myb[k] = b;
            myrec[k] = (unsigned)u | ((unsigned)(v - vlo) << 17);
            atomicAdd(&cnt[b], 1);
        }
    }
    __syncthreads();
    // exclusive scan of cnt (Hillis-Steele over 256)
    int c = cnt[t];
    offs[t] = c;
    __syncthreads();
    for (int off = 1; off < NB; off <<= 1) {
        int v = (t >= off) ? offs[t - off] : 0;
        __syncthreads();
        offs[t] += v;
        __syncthreads();
    }
    int excl = offs[t] - c;
    __syncthreads();
    offs[t] = excl;
    cur[t] = excl;
    __syncthreads();
#pragma unroll
    for (int k = 0; k < 16; ++k) {
        if (myb[k] >= 0) {
            int slot = atomicAdd(&cur[myb[k]], 1);
            stage[slot] = myrec[k];
        }
    }
    // reserve: thread t owns bucket t
    int cc = cnt[t];
    int gb = 0;
    if (cc > 0) gb = atomicAdd(&bcur[t], cc);
    gbs[t] = gb;
    __syncthreads();
    // parallel append: record r belongs to largest b with offs[b] <= r
    for (int r = t; r < total; r += 256) {
        int lo = 0, hi = NB - 1;
        while (lo < hi) {
            int m = (lo + hi + 1) >> 1;
            if (offs[m] <= r) lo = m; else hi = m - 1;
        }
        int k = r - offs[lo];
        int base = gbs[lo];
        if (base + k < CAP)                     // paranoia guard (never hits)
            brec[(size_t)lo * CAP + base + k] = stage[r];
    }
}

// ---------------- P2: scan bucket counts -> bases; + per-graph counts --------
__global__ __launch_bounds__(NB) void k_bscan(
    const int* __restrict__ bcur, int* __restrict__ bbase,
    int* __restrict__ rowstart, const int* __restrict__ gids,
    float* __restrict__ gcnt, int n_nodes, int n_edges)
{
    __shared__ int s[NB];
    int t = threadIdx.x;
    int c = min(bcur[t], CAP);
    s[t] = c;
    __syncthreads();
    for (int off = 1; off < NB; off <<= 1) {
        int v = (t >= off) ? s[t - off] : 0;
        __syncthreads();
        s[t] += v;
        __syncthreads();
    }
    bbase[t] = s[t] - c;
    if (t == 0) rowstart[n_nodes] = n_edges;
    if (t < NGR) {   // gids sorted -> per-graph node counts by binary search
        int g = t;
        int lo = 0, hi = n_nodes;
        while (lo < hi) { int m = (lo + hi) >> 1; if (gids[m] < g) lo = m + 1; else hi = m; }
        int lb = lo;
        lo = 0; hi = n_nodes;
        while (lo < hi) { int m = (lo + hi) >> 1; if (gids[m] < g + 1) lo = m + 1; else hi = m; }
        gcnt[g] = (float)(lo - lb);
    }
}

// ---------------- P3: per-bucket CSR: LDS hist + prefix -> rowstart, eidx ----
__global__ __launch_bounds__(256) void k_csr(
    const unsigned* __restrict__ brec, const int* __restrict__ bcur,
    const int* __restrict__ bbase, int* __restrict__ rowstart,
    int* __restrict__ eidx, int n_nodes)
{
    __shared__ int hist[512], scr[256];
    int b = blockIdx.x, t = threadIdx.x;
    int vlo = (b * n_nodes + NB - 1) / NB;
    int vhi = ((b + 1) * n_nodes + NB - 1) / NB;
    int nn = vhi - vlo;
    int bcnt = min(bcur[b], CAP);
    int base = bbase[b];
    for (int i = t; i < nn; i += 256) hist[i] = 0;
    __syncthreads();
    const unsigned* rec = brec + (size_t)b * CAP;
    for (int r = t; r < bcnt; r += 256)
        atomicAdd(&hist[rec[r] >> 17], 1);
    __syncthreads();
    // exclusive scan over nn (<=512) entries, 2 per thread
    int i0 = 2 * t, i1 = i0 + 1;
    int a0 = (i0 < nn) ? hist[i0] : 0;
    int a1 = (i1 < nn) ? hist[i1] : 0;
    int s2 = a0 + a1;
    scr[t] = s2;
    __syncthreads();
    for (int off = 1; off < 256; off <<= 1) {
        int v = (t >= off) ? scr[t - off] : 0;
        __syncthreads();
        scr[t] += v;
        __syncthreads();
    }
    int excl = scr[t] - s2;
    __syncthreads();
    if (i0 < nn) hist[i0] = excl;
    if (i1 < nn) hist[i1] = excl + a0;
    __syncthreads();
    for (int i = t; i < nn; i += 256) rowstart[vlo + i] = base + hist[i];
    __syncthreads();
    // scatter within the bucket window (hist now serves as per-node cursor)
    for (int r = t; r < bcnt; r += 256) {
        unsigned e = rec[r];
        int pos = atomicAdd(&hist[e >> 17], 1);
        eidx[base + pos] = (int)(e & 0x1FFFFu);
    }
}

// ---------------- D: layer-1 gather, DUAL-NODE per quad ----------------------
// eidx is streamed once -> non-temporal loads keep L2 free for featb rows.
__global__ __launch_bounds__(256) void k_agg1(
    const int* __restrict__ rowstart, const int* __restrict__ eidx,
    const unsigned* __restrict__ fbd, unsigned* __restrict__ hnbd, int n_nodes)
{
    int lane = threadIdx.x & 63;
    int quad = lane >> 4, l15 = lane & 15;
    int wglob = (int)((blockIdx.x * 256u + threadIdx.x) >> 6);
    int vA = wglob * 8 + quad * 2;
    if (vA >= n_nodes) return;
    int vB = vA + 1;
    bool hasB = (vB < n_nodes);
    int eA0 = rowstart[vA], eA1 = rowstart[vA + 1];
    int nA = eA1 - eA0;
    int eB0 = eA1, nB = 0;
    if (hasB) nB = rowstart[vB + 1] - eB0;

    // batch-0 for both nodes: issue all loads first
    int cA = min(16, nA), cB = min(16, nB);
    int idxA = 0, idxB = 0;
    if (l15 < cA) idxA = __builtin_nontemporal_load(&eidx[eA0 + l15]);
    if (l15 < cB) idxB = __builtin_nontemporal_load(&eidx[eB0 + l15]);
    unsigned uuA[16], uuB[16];
#pragma unroll
    for (int j = 0; j < 16; ++j) {
        int sA = __shfl(idxA, quad * 16 + (j < cA ? j : 0));
        uuA[j] = (j < cA) ? fbd[(size_t)sA * 16 + l15] : 0u;
    }
#pragma unroll
    for (int j = 0; j < 16; ++j) {
        int sB = __shfl(idxB, quad * 16 + (j < cB ? j : 0));
        uuB[j] = (j < cB) ? fbd[(size_t)sB * 16 + l15] : 0u;
    }
    // ---- node A: decode batch-0, drain remaining batches ----
    float a0 = 0.f, a1 = 0.f;
#pragma unroll
    for (int j = 0; j < 16; ++j) {
        a0 += bf2f((unsigned short)(uuA[j] & 0xFFFF));
        a1 += bf2f((unsigned short)(uuA[j] >> 16));
    }
    for (int base = 16; base < nA; base += 16) {
        int cnt = min(16, nA - base);
        int idx = 0;
        if (l15 < cnt) idx = __builtin_nontemporal_load(&eidx[eA0 + base + l15]);
#pragma unroll
        for (int j = 0; j < 16; ++j) {
            int s = __shfl(idx, quad * 16 + (j < cnt ? j : 0));
            uuA[j] = (j < cnt) ? fbd[(size_t)s * 16 + l15] : 0u;
        }
#pragma unroll
        for (int j = 0; j < 16; ++j) {
            a0 += bf2f((unsigned short)(uuA[j] & 0xFFFF));
            a1 += bf2f((unsigned short)(uuA[j] >> 16));
        }
    }
    {
        unsigned su = fbd[(size_t)vA * 16 + l15];        // self term (bf16 row)
        float inv = 1.0f / ((float)nA + 1.0f);
        float r0 = (a0 + bf2f((unsigned short)(su & 0xFFFF))) * inv;
        float r1 = (a1 + bf2f((unsigned short)(su >> 16))) * inv;
        hnbd[(size_t)vA * 16 + l15] =
            (unsigned)f2bf(r0) | ((unsigned)f2bf(r1) << 16);
    }
    // ---- node B ----
    if (!hasB) return;
    float b0 = 0.f, b1 = 0.f;
#pragma unroll
    for (int j = 0; j < 16; ++j) {
        b0 += bf2f((unsigned short)(uuB[j] & 0xFFFF));
        b1 += bf2f((unsigned short)(uuB[j] >> 16));
    }
    for (int base = 16; base < nB; base += 16) {
        int cnt = min(16, nB - base);
        int idx = 0;
        if (l15 < cnt) idx = __builtin_nontemporal_load(&eidx[eB0 + base + l15]);
#pragma unroll
        for (int j = 0; j < 16; ++j) {
            int s = __shfl(idx, quad * 16 + (j < cnt ? j : 0));
            uuB[j] = (j < cnt) ? fbd[(size_t)s * 16 + l15] : 0u;
        }
#pragma unroll
        for (int j = 0; j < 16; ++j) {
            b0 += bf2f((unsigned short)(uuB[j] & 0xFFFF));
            b1 += bf2f((unsigned short)(uuB[j] >> 16));
        }
    }
    {
        unsigned su = fbd[(size_t)vB * 16 + l15];
        float inv = 1.0f / ((float)nB + 1.0f);
        float r0 = (b0 + bf2f((unsigned short)(su & 0xFFFF))) * inv;
        float r1 = (b1 + bf2f((unsigned short)(su >> 16))) * inv;
        hnbd[(size_t)vB * 16 + l15] =
            (unsigned)f2bf(r0) | ((unsigned)f2bf(r1) << 16);
    }
}

// ---------------- E: MFMA node transform -> fp8 m1 DIRECTLY ------------------
__global__ __launch_bounds__(256) void k_node(
    const unsigned short* __restrict__ hnb, const unsigned short* __restrict__ W1t,
    const float* __restrict__ b1, const unsigned short* __restrict__ W2t,
    unsigned* __restrict__ m1f8, int n_nodes)
{
    __shared__ unsigned short ph[4][16 * PH_STRIDE];   // per-wave C->A transform
    int wave = threadIdx.x >> 6, lane = threadIdx.x & 63;
    int quad = lane >> 4, l15 = lane & 15;
    const f32x4 z4 = {0.f, 0.f, 0.f, 0.f};

    float bb[8];
#pragma unroll
    for (int t = 0; t < 8; ++t) bb[t] = b1[t * 16 + l15];

    for (int v0 = blockIdx.x * 64 + wave * 16; v0 < n_nodes; v0 += gridDim.x * 64) {
        bf16x8 aH = {0, 0, 0, 0, 0, 0, 0, 0};
        int vA = v0 + l15;
        if (vA < n_nodes) aH = *(const bf16x8*)&hnb[(size_t)vA * FB_DIM + quad * 8];
        f32x4 c1[8];
#pragma unroll
        for (int t = 0; t < 8; ++t) {
            bf16x8 bw = *(const bf16x8*)&W1t[(t * 16 + l15) * 32 + quad * 8];
            c1[t] = __builtin_amdgcn_mfma_f32_16x16x32_bf16(aH, bw, z4, 0, 0, 0);
        }
        float ssq[4] = {0.f, 0.f, 0.f, 0.f};
#pragma unroll
        for (int t = 0; t < 8; ++t) {
#pragma unroll
            for (int r = 0; r < 4; ++r) {
                float x = fmaxf(c1[t][r] + bb[t], 0.f);
                c1[t][r] = x;
                ssq[r] += x * x;
            }
        }
#pragma unroll
        for (int off = 1; off < 16; off <<= 1) {
#pragma unroll
            for (int r = 0; r < 4; ++r) ssq[r] += __shfl_xor(ssq[r], off);
        }
        float inv[4];
#pragma unroll
        for (int r = 0; r < 4; ++r) inv[r] = 1.0f / fmaxf(sqrtf(ssq[r]), 1e-12f);
#pragma unroll
        for (int t = 0; t < 8; ++t)
#pragma unroll
            for (int r = 0; r < 4; ++r)
                ph[wave][(quad * 4 + r) * PH_STRIDE + t * 16 + l15] =
                    f2bf(c1[t][r] * inv[r]);
        f32x4 c2[4] = {z4, z4, z4, z4};
#pragma unroll
        for (int ks = 0; ks < 4; ++ks) {
            bf16x8 aP = *(const bf16x8*)&ph[wave][l15 * PH_STRIDE + ks * 32 + quad * 8];
#pragma unroll
            for (int tn = 0; tn < 4; ++tn) {
                bf16x8 bw = *(const bf16x8*)&W2t[(tn * 16 + l15) * HID + ks * 32 + quad * 8];
                c2[tn] = __builtin_amdgcn_mfma_f32_16x16x32_bf16(aP, bw, c2[tn], 0, 0, 0);
            }
        }
#pragma unroll
        for (int r = 0; r < 4; ++r) {
            int v = v0 + quad * 4 + r;
            if (v < n_nodes) {
                unsigned pk = enc4_fp8(c2[0][r], c2[1][r], c2[2][r], c2[3][r]);
                m1f8[(size_t)v * 16 + l15] = pk;
            }
        }
    }
}

// ---------------- F: layer-2 gather + graph mean, DUAL-NODE per quad ---------
__global__ __launch_bounds__(256) void k_agg2g(
    const int* __restrict__ rowstart, const int* __restrict__ eidx,
    const unsigned* __restrict__ md, const int* __restrict__ gids,
    float* __restrict__ gpart, int n_nodes)
{
    __shared__ float lsum[NGR * OUTD];
    int per = (n_nodes + (int)gridDim.x - 1) / (int)gridDim.x;
    int v_lo = blockIdx.x * per;
    int v_hi = min(v_lo + per, n_nodes);
    if (v_lo >= n_nodes) return;
    int g_lo = gids[v_lo], g_hi = gids[v_hi - 1];
    for (int i = g_lo * OUTD + threadIdx.x; i < (g_hi + 1) * OUTD; i += 256)
        lsum[i] = 0.f;
    __syncthreads();

    int lane = threadIdx.x & 63;
    int wave = threadIdx.x >> 6;
    int quad = lane >> 4, l15 = lane & 15;
    int curg = -1;
    f32x2 c01 = {0.f, 0.f}, c23 = {0.f, 0.f};
    for (int vb = v_lo + wave * 8; vb < v_hi; vb += 32) {
        int vA = vb + quad * 2;
        if (vA >= v_hi) continue;
        int vB = vA + 1;
        bool hasB = (vB < v_hi);
        int eA0 = rowstart[vA], eA1 = rowstart[vA + 1];
        int nA = eA1 - eA0;
        int eB0 = eA1, nB = 0;
        if (hasB) nB = rowstart[vB + 1] - eB0;

        // batch-0 for both nodes: all loads first
        int cA = min(16, nA), cB = min(16, nB);
        int idxA = 0, idxB = 0;
        if (l15 < cA) idxA = __builtin_nontemporal_load(&eidx[eA0 + l15]);
        if (l15 < cB) idxB = __builtin_nontemporal_load(&eidx[eB0 + l15]);
        unsigned uuA[16], uuB[16];
#pragma unroll
        for (int j = 0; j < 16; ++j) {
            int s = __shfl(idxA, quad * 16 + (j < cA ? j : 0));
            uuA[j] = (j < cA) ? md[(size_t)s * 16 + l15] : 0u;
        }
#pragma unroll
        for (int j = 0; j < 16; ++j) {
            int s = __shfl(idxB, quad * 16 + (j < cB ? j : 0));
            uuB[j] = (j < cB) ? md[(size_t)s * 16 + l15] : 0u;
        }
        // ---- node A ----
        f32x2 a01 = {0.f, 0.f}, a23 = {0.f, 0.f};
#pragma unroll
        for (int j = 0; j < 16; ++j) {
            f32x2 lo, hi;
            dec_pk(uuA[j], lo, hi);
            a01 += lo; a23 += hi;
        }
        for (int base = 16; base < nA; base += 16) {
            int cnt = min(16, nA - base);
            int idx = 0;
            if (l15 < cnt) idx = __builtin_nontemporal_load(&eidx[eA0 + base + l15]);
#pragma unroll
            for (int j = 0; j < 16; ++j) {
                int s = __shfl(idx, quad * 16 + (j < cnt ? j : 0));
                uuA[j] = (j < cnt) ? md[(size_t)s * 16 + l15] : 0u;
            }
#pragma unroll
            for (int j = 0; j < 16; ++j) {
                f32x2 lo, hi;
                dec_pk(uuA[j], lo, hi);
                a01 += lo; a23 += hi;
            }
        }
        {
            f32x2 lo, hi;
            dec_pk(md[(size_t)vA * 16 + l15], lo, hi);   // self term
            a01 += lo; a23 += hi;
        }
        {
            float inv = 1.0f / ((float)nA + 1.0f);
            int g = gids[vA];
            if (g != curg) {
                if (curg >= 0) {
                    atomicAdd(&lsum[curg * OUTD + l15 +  0], c01[0]);
                    atomicAdd(&lsum[curg * OUTD + l15 + 16], c01[1]);
                    atomicAdd(&lsum[curg * OUTD + l15 + 32], c23[0]);
                    atomicAdd(&lsum[curg * OUTD + l15 + 48], c23[1]);
                }
                curg = g;
                c01[0] = a01[0] * inv; c01[1] = a01[1] * inv;
                c23[0] = a23[0] * inv; c23[1] = a23[1] * inv;
            } else {
                c01[0] += a01[0] * inv; c01[1] += a01[1] * inv;
                c23[0] += a23[0] * inv; c23[1] += a23[1] * inv;
            }
        }
        // ---- node B ----
        if (!hasB) continue;
        f32x2 b01 = {0.f, 0.f}, b23 = {0.f, 0.f};
#pragma unroll
        for (int j = 0; j < 16; ++j) {
            f32x2 lo, hi;
            dec_pk(uuB[j], lo, hi);
            b01 += lo; b23 += hi;
        }
        for (int base = 16; base < nB; base += 16) {
            int cnt = min(16, nB - base);
            int idx = 0;
            if (l15 < cnt) idx = __builtin_nontemporal_load(&eidx[eB0 + base + l15]);
#pragma unroll
            for (int j = 0; j < 16; ++j) {
                int s = __shfl(idx, quad * 16 + (j < cnt ? j : 0));
                uuB[j] = (j < cnt) ? md[(size_t)s * 16 + l15] : 0u;
            }
#pragma unroll
            for (int j = 0; j < 16; ++j) {
                f32x2 lo, hi;
                dec_pk(uuB[j], lo, hi);
                b01 += lo; b23 += hi;
            }
        }
        {
            f32x2 lo, hi;
            dec_pk(md[(size_t)vB * 16 + l15], lo, hi);   // self term
            b01 += lo; b23 += hi;
        }
        {
            float inv = 1.0f / ((float)nB + 1.0f);
            int g = gids[vB];
            if (g != curg) {
                if (curg >= 0) {
                    atomicAdd(&lsum[curg * OUTD + l15 +  0], c01[0]);
                    atomicAdd(&lsum[curg * OUTD + l15 + 16], c01[1]);
                    atomicAdd(&lsum[curg * OUTD + l15 + 32], c23[0]);
                    atomicAdd(&lsum[curg * OUTD + l15 + 48], c23[1]);
                }
                curg = g;
                c01[0] = b01[0] * inv; c01[1] = b01[1] * inv;
                c23[0] = b23[0] * inv; c23[1] = b23[1] * inv;
            } else {
                c01[0] += b01[0] * inv; c01[1] += b01[1] * inv;
                c23[0] += b23[0] * inv; c23[1] += b23[1] * inv;
            }
        }
    }
    if (curg >= 0) {
        atomicAdd(&lsum[curg * OUTD + l15 +  0], c01[0]);
        atomicAdd(&lsum[curg * OUTD + l15 + 16], c01[1]);
        atomicAdd(&lsum[curg * OUTD + l15 + 32], c23[0]);
        atomicAdd(&lsum[curg * OUTD + l15 + 48], c23[1]);
    }
    __syncthreads();
    float* gp = gpart + (size_t)xcd_id() * NGR * OUTD;
    for (int i = g_lo * OUTD + threadIdx.x; i < (g_hi + 1) * OUTD; i += 256)
        atomicAdd(&gp[i], lsum[i]);
}

// ---------------- G: finalize: reduce the 8 XCD partials, mean + b2 ----------
__global__ __launch_bounds__(256) void k_final(
    const float* __restrict__ gpart, const float* __restrict__ gcnt,
    const float* __restrict__ b2, float* __restrict__ out)
{
    int i = blockIdx.x * 256 + threadIdx.x;
    if (i >= NGR * OUTD) return;
    int g = i >> 6, d = i & 63;
    float s = 0.f;
#pragma unroll
    for (int p = 0; p < NXCD; ++p) s += gpart[(size_t)p * NGR * OUTD + i];
    float c = gcnt[g];
    out[i] = (c > 0.f) ? (s / c + b2[d]) : 0.f;
}

extern "C" void kernel_launch(void* const* d_in, const int* in_sizes, int n_in,
                              void* d_out, int out_size, void* d_ws, size_t ws_size,
                              hipStream_t stream) {
    const float* feat0 = (const float*)d_in[0];
    const float* W1    = (const float*)d_in[1];
    const float* b1    = (const float*)d_in[2];
    const float* W2    = (const float*)d_in[3];
    const float* b2    = (const float*)d_in[4];
    const int*   src   = (const int*)d_in[5];
    const int*   dst   = (const int*)d_in[6];
    const int*   gids  = (const int*)d_in[7];
    int n_edges = in_sizes[5];
    int n_nodes = in_sizes[7];

    // ---- workspace layout (~22MB) ----
    unsigned short* W1t = (unsigned short*)d_ws;                    // 8KB
    unsigned short* W2t = W1t + HID * 32;                           // 16KB
    unsigned short* featb = W2t + (size_t)OUTD * HID;               // n*64B
    unsigned* m1f8 = (unsigned*)featb;                              // alias (after agg1)
    char* up = (char*)(featb + (size_t)n_nodes * FB_DIM);
    up = (char*)(((uintptr_t)up + 15) & ~(uintptr_t)15);
    unsigned short* hnb = (unsigned short*)up;
    unsigned* brec = (unsigned*)up;                                 // alias
    size_t usz = (size_t)n_nodes * FB_DIM * 2;
    size_t rsz = (size_t)NB * CAP * 4;
    char* after = up + (usz > rsz ? usz : rsz);
    after = (char*)(((uintptr_t)after + 15) & ~(uintptr_t)15);
    int*   eidx     = (int*)after;                                  // n_edges*4B
    int*   rowstart = eidx + n_edges;                               // (n+1)*4B
    int*   bcur     = rowstart + n_nodes + 1;                       // NB
    int*   bbase    = bcur + NB;                                    // NB
    float* gpart    = (float*)(bbase + NB);                         // 8*16KB
    float* gcnt     = gpart + (size_t)NXCD * NGR * OUTD;            // NGR

    // zero: bcur | bbase | gpart | gcnt (contiguous)
    size_t zero_units = 2 * NB + (size_t)NXCD * NGR * OUTD + NGR;
    hipMemsetAsync(bcur, 0, zero_units * 4, stream);

    long long prep_items = (long long)n_nodes * FB_DIM + HID * 32 + OUTD * HID;
    k_prep<<<(unsigned)((prep_items + 255) / 256), 256, 0, stream>>>(
        feat0, featb, W1, W2, W1t, W2t, n_nodes);

    // ---- CSR build: bin -> scan(+gcnt) -> per-bucket fill ----
    unsigned blkB = (unsigned)((n_edges + CHUNK - 1) / CHUNK);
    k_bin<<<blkB, 256, 0, stream>>>(src, dst, brec, bcur, n_edges, n_nodes);
    k_bscan<<<1, NB, 0, stream>>>(bcur, bbase, rowstart, gids, gcnt,
                                  n_nodes, n_edges);
    k_csr<<<NB, 256, 0, stream>>>(brec, bcur, bbase, rowstart, eidx, n_nodes);

    // dual-node quads: 32 nodes per 256-thread block
    unsigned blkA = (unsigned)((n_nodes + 31) / 32);
    k_agg1<<<blkA, 256, 0, stream>>>(rowstart, eidx, (const unsigned*)featb,
                                     (unsigned*)hnb, n_nodes);

    unsigned blkN = (unsigned)((n_nodes + 63) / 64);
    k_node<<<blkN, 256, 0, stream>>>(hnb, W1t, b1, W2t, m1f8, n_nodes);

    k_agg2g<<<A2_BLOCKS, 256, 0, stream>>>(rowstart, eidx, m1f8, gids, gpart,
                                           n_nodes);

    k_final<<<(NGR * OUTD + 255) / 256, 256, 0, stream>>>(gpart, gcnt, b2,
                                                          (float*)d_out);
}

// Round 10
// 223.985 us; speedup vs baseline: 1.0568x; 1.0568x over previous
//
#include <hip/hip_runtime.h>

#define IN_DIM 23
#define HID 128
#define OUTD 64
#define NGR 64
#define NXCD 8
#define FB_DIM 32      // feat padded to 32 bf16 = 64B aligned rows
#define PH_STRIDE 136  // 16 rows x 136 bf16: 272B row stride (16B-aligned, bank-spread)
#define A2_BLOCKS 2048
#define NB 256         // dst-range buckets for CSR build
#define CAP 8192       // records per bucket region (mean 6250, sd 79 -> +24 sigma)
#define CHUNK 4096     // edges staged per k_bin block (16/thread in regs)

typedef __attribute__((ext_vector_type(8))) short bf16x8;
typedef __attribute__((ext_vector_type(4))) float f32x4;
typedef __attribute__((ext_vector_type(2))) float f32x2;

static __device__ __forceinline__ unsigned xcd_id() {
    unsigned x;
    asm volatile("s_getreg_b32 %0, hwreg(20, 0, 32)" : "=s"(x));  // HW_REG_XCC_ID
    return x & (NXCD - 1);
}

static __device__ __forceinline__ unsigned short f2bf(float x) {
    unsigned u = __float_as_uint(x);
    unsigned r = (u + 0x7FFFu + ((u >> 16) & 1u)) >> 16;   // RNE
    return (unsigned short)r;
}
static __device__ __forceinline__ float bf2f(unsigned short u) {
    return __uint_as_float((unsigned)u << 16);             // exact
}

// ---- fp8 e4m3 (OCP) scalar encode: RNE, satfinite (fallback path) -----------
static __device__ __forceinline__ unsigned enc_fp8(float x) {
    float a = fabsf(x);
    unsigned s = (__float_as_uint(x) >> 31) << 7;
    if (!(a > 0.f)) return s;                    // zero
    a = fminf(a, 448.f);
    int eb; float fr = frexpf(a, &eb);           // a = fr*2^eb, fr in [0.5,1)
    int E = eb - 1;
    int code;
    if (E < -6) code = (int)rintf(ldexpf(a, 9)); // denormal path
    else        code = ((E + 7) << 3) + (int)rintf(ldexpf(fr, 4)) - 8;
    code = min(code, 0x7E);
    return s | (unsigned)code;
}

// ---- fp8 e4m3 pack 4: HW packed convert if available ------------------------
#if __has_builtin(__builtin_amdgcn_cvt_pk_fp8_f32)
static __device__ __forceinline__ unsigned enc4_fp8(float a, float b,
                                                    float c, float d) {
    int r = __builtin_amdgcn_cvt_pk_fp8_f32(a, b, 0, false);
    r = __builtin_amdgcn_cvt_pk_fp8_f32(c, d, r, true);
    return (unsigned)r;
}
#else
static __device__ __forceinline__ unsigned enc4_fp8(float a, float b,
                                                    float c, float d) {
    return enc_fp8(a) | (enc_fp8(b) << 8) | (enc_fp8(c) << 16)
         | (enc_fp8(d) << 24);
}
#endif

// ---- fp8 e4m3 decode 4 -> two packed f32x2 ----------------------------------
#if __has_builtin(__builtin_amdgcn_cvt_pk_f32_fp8)
static __device__ __forceinline__ void dec_pk(unsigned u, f32x2& lo, f32x2& hi) {
    lo = __builtin_amdgcn_cvt_pk_f32_fp8((int)u, false);
    hi = __builtin_amdgcn_cvt_pk_f32_fp8((int)u, true);
}
#else
static __device__ __forceinline__ float dec1_fp8(unsigned b) {
    unsigned s = (b & 0x80u) << 24;
    unsigned em = b & 0x7Fu;
    float f = __uint_as_float(s | ((em << 20) + 0x3C000000u));
    if ((b & 0x78u) == 0)
        f = 2.f * f - __uint_as_float(s | 0x3C800000u);
    return f;
}
static __device__ __forceinline__ void dec_pk(unsigned u, f32x2& lo, f32x2& hi) {
    lo[0] = dec1_fp8(u & 0xFF);        lo[1] = dec1_fp8((u >> 8) & 0xFF);
    hi[0] = dec1_fp8((u >> 16) & 0xFF); hi[1] = dec1_fp8(u >> 24);
}
#endif

// ---------------- A: fused prep: feat0 -> bf16 rows; W1/W2 transpose+pad -----
__global__ __launch_bounds__(256) void k_prep(
    const float* __restrict__ feat0, unsigned short* __restrict__ featb,
    const float* __restrict__ W1, const float* __restrict__ W2,
    unsigned short* __restrict__ W1t, unsigned short* __restrict__ W2t,
    int n_nodes)
{
    int i = blockIdx.x * 256 + threadIdx.x;
    int nf = n_nodes * FB_DIM;
    if (i < nf) {
        int v = i >> 5, d = i & (FB_DIM - 1);
        float x = (d < IN_DIM) ? feat0[(size_t)v * IN_DIM + d] : 0.f;
        featb[i] = f2bf(x);
    } else {
        int j = i - nf;
        if (j < HID * 32) {
            int h = j >> 5, d = j & 31;
            W1t[j] = f2bf((d < IN_DIM) ? W1[d * HID + h] : 0.f);
        } else if (j < HID * 32 + OUTD * HID) {
            int q = j - HID * 32;
            int o = q >> 7, k = q & 127;
            W2t[q] = f2bf(W2[k * OUTD + o]);
        }
    }
}

// ---------------- P1: bucket edges by dst range (regs -> LDS -> append) ------
// Single global read: CHUNK edges into registers (16/thread), LDS bucket
// count, scan, reorder from regs into bucket-contiguous LDS, then one global
// atomic per bucket reserves space and records append contiguously (serial
// per-thread append measured faster than per-record binary search, R9).
__global__ __launch_bounds__(256) void k_bin(
    const int* __restrict__ src, const int* __restrict__ dst,
    unsigned* __restrict__ brec, int* __restrict__ bcur,
    int n_edges, int n_nodes)
{
    __shared__ int cnt[NB], offs[NB], cur[NB];
    __shared__ unsigned stage[CHUNK];
    int t = threadIdx.x;
    int e0 = blockIdx.x * CHUNK;
    int e1 = min(e0 + CHUNK, n_edges);
    int myb[16];
    unsigned myrec[16];
    cnt[t] = 0;
    __syncthreads();
#pragma unroll
    for (int k = 0; k < 16; ++k) {
        int e = e0 + k * 256 + t;
        myb[k] = -1;
        if (e < e1) {
            int u = src[e], v = dst[e];
            int b = (v * NB) / n_nodes;                    // exact int div
            int vlo = (b * n_nodes + NB - 1) / NB;
            myb[k] = b;
            myrec[k] = (unsigned)u | ((unsigned)(v - vlo) << 17);
            atomicAdd(&cnt[b], 1);
        }
    }
    __syncthreads();
    // exclusive scan of cnt (Hillis-Steele over 256)
    int c = cnt[t];
    offs[t] = c;
    __syncthreads();
    for (int off = 1; off < NB; off <<= 1) {
        int v = (t >= off) ? offs[t - off] : 0;
        __syncthreads();
        offs[t] += v;
        __syncthreads();
    }
    int excl = offs[t] - c;
    __syncthreads();
    offs[t] = excl;
    cur[t] = excl;
    __syncthreads();
#pragma unroll
    for (int k = 0; k < 16; ++k) {
        if (myb[k] >= 0) {
            int slot = atomicAdd(&cur[myb[k]], 1);
            stage[slot] = myrec[k];
        }
    }
    __syncthreads();
    // reserve + append: thread t owns bucket t
    int cc = cnt[t];
    int gb = 0;
    if (cc > 0) gb = atomicAdd(&bcur[t], cc);
    if (gb + cc > CAP) cc = max(0, CAP - gb);   // paranoia guard (never hits)
    unsigned* dp = brec + (size_t)t * CAP + gb;
    int sb = offs[t];
    for (int k = 0; k < cc; ++k) dp[k] = stage[sb + k];
}

// ---------------- P2: scan bucket counts -> bases; + per-graph counts --------
__global__ __launch_bounds__(NB) void k_bscan(
    const int* __restrict__ bcur, int* __restrict__ bbase,
    int* __restrict__ rowstart, const int* __restrict__ gids,
    float* __restrict__ gcnt, int n_nodes, int n_edges)
{
    __shared__ int s[NB];
    int t = threadIdx.x;
    int c = min(bcur[t], CAP);
    s[t] = c;
    __syncthreads();
    for (int off = 1; off < NB; off <<= 1) {
        int v = (t >= off) ? s[t - off] : 0;
        __syncthreads();
        s[t] += v;
        __syncthreads();
    }
    bbase[t] = s[t] - c;
    if (t == 0) rowstart[n_nodes] = n_edges;
    if (t < NGR) {   // gids sorted -> per-graph node counts by binary search
        int g = t;
        int lo = 0, hi = n_nodes;
        while (lo < hi) { int m = (lo + hi) >> 1; if (gids[m] < g) lo = m + 1; else hi = m; }
        int lb = lo;
        lo = 0; hi = n_nodes;
        while (lo < hi) { int m = (lo + hi) >> 1; if (gids[m] < g + 1) lo = m + 1; else hi = m; }
        gcnt[g] = (float)(lo - lb);
    }
}

// ---------------- P3: per-bucket CSR: LDS hist + prefix -> rowstart, eidx ----
__global__ __launch_bounds__(256) void k_csr(
    const unsigned* __restrict__ brec, const int* __restrict__ bcur,
    const int* __restrict__ bbase, int* __restrict__ rowstart,
    int* __restrict__ eidx, int n_nodes)
{
    __shared__ int hist[512], scr[256];
    int b = blockIdx.x, t = threadIdx.x;
    int vlo = (b * n_nodes + NB - 1) / NB;
    int vhi = ((b + 1) * n_nodes + NB - 1) / NB;
    int nn = vhi - vlo;
    int bcnt = min(bcur[b], CAP);
    int base = bbase[b];
    for (int i = t; i < nn; i += 256) hist[i] = 0;
    __syncthreads();
    const unsigned* rec = brec + (size_t)b * CAP;
    for (int r = t; r < bcnt; r += 256)
        atomicAdd(&hist[rec[r] >> 17], 1);
    __syncthreads();
    // exclusive scan over nn (<=512) entries, 2 per thread
    int i0 = 2 * t, i1 = i0 + 1;
    int a0 = (i0 < nn) ? hist[i0] : 0;
    int a1 = (i1 < nn) ? hist[i1] : 0;
    int s2 = a0 + a1;
    scr[t] = s2;
    __syncthreads();
    for (int off = 1; off < 256; off <<= 1) {
        int v = (t >= off) ? scr[t - off] : 0;
        __syncthreads();
        scr[t] += v;
        __syncthreads();
    }
    int excl = scr[t] - s2;
    __syncthreads();
    if (i0 < nn) hist[i0] = excl;
    if (i1 < nn) hist[i1] = excl + a0;
    __syncthreads();
    for (int i = t; i < nn; i += 256) rowstart[vlo + i] = base + hist[i];
    __syncthreads();
    // scatter within the bucket window (hist now serves as per-node cursor)
    for (int r = t; r < bcnt; r += 256) {
        unsigned e = rec[r];
        int pos = atomicAdd(&hist[e >> 17], 1);
        eidx[base + pos] = (int)(e & 0x1FFFFu);
    }
}

// ---------------- D: layer-1 gather, QUAD-PER-NODE ---------------------------
__global__ __launch_bounds__(256) void k_agg1(
    const int* __restrict__ rowstart, const int* __restrict__ eidx,
    const unsigned* __restrict__ fbd, unsigned* __restrict__ hnbd, int n_nodes)
{
    int lane = threadIdx.x & 63;
    int quad = lane >> 4, l15 = lane & 15;
    int wglob = (int)((blockIdx.x * 256u + threadIdx.x) >> 6);
    int v = wglob * 4 + quad;
    if (v >= n_nodes) return;
    int e0 = rowstart[v], e1 = rowstart[v + 1];
    int nedge = e1 - e0;
    float a0 = 0.f, a1 = 0.f;
    for (int base = 0; base < nedge; base += 16) {
        int cnt = min(16, nedge - base);
        int idx = 0;
        if (l15 < cnt) idx = eidx[e0 + base + l15];
        unsigned uu[16];
#pragma unroll
        for (int j = 0; j < 16; ++j) {
            int s = __shfl(idx, quad * 16 + min(j, cnt - 1));
            uu[j] = 0u;
            if (j < cnt) uu[j] = fbd[(size_t)s * 16 + l15];
        }
#pragma unroll
        for (int j = 0; j < 16; ++j) {
            a0 += bf2f((unsigned short)(uu[j] & 0xFFFF));
            a1 += bf2f((unsigned short)(uu[j] >> 16));
        }
    }
    unsigned su = fbd[(size_t)v * 16 + l15];            // self term (bf16 row)
    float inv = 1.0f / ((float)nedge + 1.0f);
    float r0 = (a0 + bf2f((unsigned short)(su & 0xFFFF))) * inv;
    float r1 = (a1 + bf2f((unsigned short)(su >> 16))) * inv;
    hnbd[(size_t)v * 16 + l15] = (unsigned)f2bf(r0) | ((unsigned)f2bf(r1) << 16);
}

// ---------------- E: MFMA node transform -> fp8 m1 DIRECTLY ------------------
// m1f8 layout: dword l15 of row v packs dims {l15, l15+16, l15+32, l15+48}
// (lane-local: each lane owns exactly its 4 accumulator values).
__global__ __launch_bounds__(256) void k_node(
    const unsigned short* __restrict__ hnb, const unsigned short* __restrict__ W1t,
    const float* __restrict__ b1, const unsigned short* __restrict__ W2t,
    unsigned* __restrict__ m1f8, int n_nodes)
{
    __shared__ unsigned short ph[4][16 * PH_STRIDE];   // per-wave C->A transform
    int wave = threadIdx.x >> 6, lane = threadIdx.x & 63;
    int quad = lane >> 4, l15 = lane & 15;
    const f32x4 z4 = {0.f, 0.f, 0.f, 0.f};

    float bb[8];
#pragma unroll
    for (int t = 0; t < 8; ++t) bb[t] = b1[t * 16 + l15];

    for (int v0 = blockIdx.x * 64 + wave * 16; v0 < n_nodes; v0 += gridDim.x * 64) {
        bf16x8 aH = {0, 0, 0, 0, 0, 0, 0, 0};
        int vA = v0 + l15;
        if (vA < n_nodes) aH = *(const bf16x8*)&hnb[(size_t)vA * FB_DIM + quad * 8];
        f32x4 c1[8];
#pragma unroll
        for (int t = 0; t < 8; ++t) {
            bf16x8 bw = *(const bf16x8*)&W1t[(t * 16 + l15) * 32 + quad * 8];
            c1[t] = __builtin_amdgcn_mfma_f32_16x16x32_bf16(aH, bw, z4, 0, 0, 0);
        }
        float ssq[4] = {0.f, 0.f, 0.f, 0.f};
#pragma unroll
        for (int t = 0; t < 8; ++t) {
#pragma unroll
            for (int r = 0; r < 4; ++r) {
                float x = fmaxf(c1[t][r] + bb[t], 0.f);
                c1[t][r] = x;
                ssq[r] += x * x;
            }
        }
#pragma unroll
        for (int off = 1; off < 16; off <<= 1) {
#pragma unroll
            for (int r = 0; r < 4; ++r) ssq[r] += __shfl_xor(ssq[r], off);
        }
        float inv[4];
#pragma unroll
        for (int r = 0; r < 4; ++r) inv[r] = 1.0f / fmaxf(sqrtf(ssq[r]), 1e-12f);
#pragma unroll
        for (int t = 0; t < 8; ++t)
#pragma unroll
            for (int r = 0; r < 4; ++r)
                ph[wave][(quad * 4 + r) * PH_STRIDE + t * 16 + l15] =
                    f2bf(c1[t][r] * inv[r]);
        f32x4 c2[4] = {z4, z4, z4, z4};
#pragma unroll
        for (int ks = 0; ks < 4; ++ks) {
            bf16x8 aP = *(const bf16x8*)&ph[wave][l15 * PH_STRIDE + ks * 32 + quad * 8];
#pragma unroll
            for (int tn = 0; tn < 4; ++tn) {
                bf16x8 bw = *(const bf16x8*)&W2t[(tn * 16 + l15) * HID + ks * 32 + quad * 8];
                c2[tn] = __builtin_amdgcn_mfma_f32_16x16x32_bf16(aP, bw, c2[tn], 0, 0, 0);
            }
        }
#pragma unroll
        for (int r = 0; r < 4; ++r) {
            int v = v0 + quad * 4 + r;
            if (v < n_nodes) {
                unsigned pk = enc4_fp8(c2[0][r], c2[1][r], c2[2][r], c2[3][r]);
                m1f8[(size_t)v * 16 + l15] = pk;
            }
        }
    }
}

// ---------------- F: layer-2 gather + graph mean, CONTIGUOUS CHUNKS ----------
// dword -> dims {l15, l15+16, l15+32, l15+48} (matches k_node's packing).
__global__ __launch_bounds__(256) void k_agg2g(
    const int* __restrict__ rowstart, const int* __restrict__ eidx,
    const unsigned* __restrict__ md, const int* __restrict__ gids,
    float* __restrict__ gpart, int n_nodes)
{
    __shared__ float lsum[NGR * OUTD];
    int per = (n_nodes + (int)gridDim.x - 1) / (int)gridDim.x;
    int v_lo = blockIdx.x * per;
    int v_hi = min(v_lo + per, n_nodes);
    if (v_lo >= n_nodes) return;
    int g_lo = gids[v_lo], g_hi = gids[v_hi - 1];
    for (int i = g_lo * OUTD + threadIdx.x; i < (g_hi + 1) * OUTD; i += 256)
        lsum[i] = 0.f;
    __syncthreads();

    int lane = threadIdx.x & 63;
    int wave = threadIdx.x >> 6;
    int quad = lane >> 4, l15 = lane & 15;
    int curg = -1;
    f32x2 c01 = {0.f, 0.f}, c23 = {0.f, 0.f};
    for (int v = v_lo + wave * 4 + quad; v < v_hi; v += 16) {
        int e0 = rowstart[v], e1 = rowstart[v + 1];
        int nedge = e1 - e0;
        f32x2 a01 = {0.f, 0.f}, a23 = {0.f, 0.f};
        for (int base = 0; base < nedge; base += 16) {
            int cnt = min(16, nedge - base);
            int idx = 0;
            if (l15 < cnt) idx = eidx[e0 + base + l15];
            unsigned uu[16];
#pragma unroll
            for (int j = 0; j < 16; ++j) {
                int s = __shfl(idx, quad * 16 + min(j, cnt - 1));
                uu[j] = 0u;
                if (j < cnt) uu[j] = md[(size_t)s * 16 + l15];
            }
#pragma unroll
            for (int j = 0; j < 16; ++j) {
                f32x2 lo, hi;
                dec_pk(uu[j], lo, hi);
                a01 += lo; a23 += hi;
            }
        }
        // self term
        {
            f32x2 lo, hi;
            dec_pk(md[(size_t)v * 16 + l15], lo, hi);
            a01 += lo; a23 += hi;
        }
        float inv = 1.0f / ((float)nedge + 1.0f);
        int g = gids[v];
        if (g != curg) {
            if (curg >= 0) {
                atomicAdd(&lsum[curg * OUTD + l15 +  0], c01[0]);
                atomicAdd(&lsum[curg * OUTD + l15 + 16], c01[1]);
                atomicAdd(&lsum[curg * OUTD + l15 + 32], c23[0]);
                atomicAdd(&lsum[curg * OUTD + l15 + 48], c23[1]);
            }
            curg = g;
            c01[0] = a01[0] * inv; c01[1] = a01[1] * inv;
            c23[0] = a23[0] * inv; c23[1] = a23[1] * inv;
        } else {
            c01[0] += a01[0] * inv; c01[1] += a01[1] * inv;
            c23[0] += a23[0] * inv; c23[1] += a23[1] * inv;
        }
    }
    if (curg >= 0) {
        atomicAdd(&lsum[curg * OUTD + l15 +  0], c01[0]);
        atomicAdd(&lsum[curg * OUTD + l15 + 16], c01[1]);
        atomicAdd(&lsum[curg * OUTD + l15 + 32], c23[0]);
        atomicAdd(&lsum[curg * OUTD + l15 + 48], c23[1]);
    }
    __syncthreads();
    float* gp = gpart + (size_t)xcd_id() * NGR * OUTD;
    for (int i = g_lo * OUTD + threadIdx.x; i < (g_hi + 1) * OUTD; i += 256)
        atomicAdd(&gp[i], lsum[i]);
}

// ---------------- G: finalize: reduce the 8 XCD partials, mean + b2 ----------
__global__ __launch_bounds__(256) void k_final(
    const float* __restrict__ gpart, const float* __restrict__ gcnt,
    const float* __restrict__ b2, float* __restrict__ out)
{
    int i = blockIdx.x * 256 + threadIdx.x;
    if (i >= NGR * OUTD) return;
    int g = i >> 6, d = i & 63;
    float s = 0.f;
#pragma unroll
    for (int p = 0; p < NXCD; ++p) s += gpart[(size_t)p * NGR * OUTD + i];
    float c = gcnt[g];
    out[i] = (c > 0.f) ? (s / c + b2[d]) : 0.f;
}

extern "C" void kernel_launch(void* const* d_in, const int* in_sizes, int n_in,
                              void* d_out, int out_size, void* d_ws, size_t ws_size,
                              hipStream_t stream) {
    const float* feat0 = (const float*)d_in[0];
    const float* W1    = (const float*)d_in[1];
    const float* b1    = (const float*)d_in[2];
    const float* W2    = (const float*)d_in[3];
    const float* b2    = (const float*)d_in[4];
    const int*   src   = (const int*)d_in[5];
    const int*   dst   = (const int*)d_in[6];
    const int*   gids  = (const int*)d_in[7];
    int n_edges = in_sizes[5];
    int n_nodes = in_sizes[7];

    // ---- workspace layout (~22MB) ----
    unsigned short* W1t = (unsigned short*)d_ws;                    // 8KB
    unsigned short* W2t = W1t + HID * 32;                           // 16KB
    unsigned short* featb = W2t + (size_t)OUTD * HID;               // n*64B
    unsigned* m1f8 = (unsigned*)featb;                              // alias (after agg1)
    char* up = (char*)(featb + (size_t)n_nodes * FB_DIM);
    up = (char*)(((uintptr_t)up + 15) & ~(uintptr_t)15);
    unsigned short* hnb = (unsigned short*)up;
    unsigned* brec = (unsigned*)up;                                 // alias
    size_t usz = (size_t)n_nodes * FB_DIM * 2;
    size_t rsz = (size_t)NB * CAP * 4;
    char* after = up + (usz > rsz ? usz : rsz);
    after = (char*)(((uintptr_t)after + 15) & ~(uintptr_t)15);
    int*   eidx     = (int*)after;                                  // n_edges*4B
    int*   rowstart = eidx + n_edges;                               // (n+1)*4B
    int*   bcur     = rowstart + n_nodes + 1;                       // NB
    int*   bbase    = bcur + NB;                                    // NB
    float* gpart    = (float*)(bbase + NB);                         // 8*16KB
    float* gcnt     = gpart + (size_t)NXCD * NGR * OUTD;            // NGR

    // zero: bcur | bbase | gpart | gcnt (contiguous)
    size_t zero_units = 2 * NB + (size_t)NXCD * NGR * OUTD + NGR;
    hipMemsetAsync(bcur, 0, zero_units * 4, stream);

    long long prep_items = (long long)n_nodes * FB_DIM + HID * 32 + OUTD * HID;
    k_prep<<<(unsigned)((prep_items + 255) / 256), 256, 0, stream>>>(
        feat0, featb, W1, W2, W1t, W2t, n_nodes);

    // ---- CSR build: bin -> scan(+gcnt) -> per-bucket fill ----
    unsigned blkB = (unsigned)((n_edges + CHUNK - 1) / CHUNK);
    k_bin<<<blkB, 256, 0, stream>>>(src, dst, brec, bcur, n_edges, n_nodes);
    k_bscan<<<1, NB, 0, stream>>>(bcur, bbase, rowstart, gids, gcnt,
                                  n_nodes, n_edges);
    k_csr<<<NB, 256, 0, stream>>>(brec, bcur, bbase, rowstart, eidx, n_nodes);

    // quad-per-node: 16 nodes per 256-thread block
    unsigned blkA = (unsigned)((n_nodes + 15) / 16);
    k_agg1<<<blkA, 256, 0, stream>>>(rowstart, eidx, (const unsigned*)featb,
                                     (unsigned*)hnb, n_nodes);

    k_node<<<1024, 256, 0, stream>>>(hnb, W1t, b1, W2t, m1f8, n_nodes);

    k_agg2g<<<A2_BLOCKS, 256, 0, stream>>>(rowstart, eidx, m1f8, gids, gpart,
                                           n_nodes);

    k_final<<<(NGR * OUTD + 255) / 256, 256, 0, stream>>>(gpart, gcnt, b2,
                                                          (float*)d_out);
}